// Round 5
// baseline (188.177 us; speedup 1.0000x reference)
//
#include <hip/hip_runtime.h>

// LowRankGDN: out[n,c,p] = x[n,c,p] * rsqrt( beta_r[c] + sum_r A_r[c,r] * T[n,r,p] )
//   T[n,r,p] = sum_c A_r[c,r] * x[n,c,p]^2
// Shapes: x [8,192,256,256] f32, beta [192], A [192,8]. Output f32, same shape.
//
// R5: single-pass, x in registers, FLOAT2 accesses (8B/lane, 512B/wave-instr)
// to halve memory instruction count vs R4's scalar dwords (R4 = 4.8 TB/s
// effective, 77% of float4-copy ceiling). 512-thr block = 8 slices x 64 lanes,
// 128 px/block, 24 ch/thread as float2. VGPR ~84 -> launch_bounds(512,6),
// 3 blocks/CU (75% occ). Reduce: partials -> fold 8->4 -> sum 4; T regs
// reused as final Tf to cap VGPR.

#define N_IMG 8
#define C_CH 192
#define R_RK 8
#define HW 65536              // 256*256
#define PXB 128               // pixels per block (64 lanes * 2)
#define CSLICES 8
#define CPT (C_CH / CSLICES)  // 24 channels per thread
#define NTHR 512
#define BLOCKS_PER_IMG (HW / PXB)    // 512

#define PEDESTAL_F 1.4551915228366852e-11f    // 2^-36
#define BOUND_A_F 3.814697265625e-06f         // 2^-18 = sqrt(pedestal)
#define BOUND_BETA_F 1.0000072759311364e-03f  // sqrt(1e-6 + 2^-36)

typedef float v2 __attribute__((ext_vector_type(2)));

__global__ __launch_bounds__(NTHR, 6) void lrgdn_kernel(
    const float* __restrict__ x,
    const float* __restrict__ beta,
    const float* __restrict__ A,
    float* __restrict__ out)
{
    __shared__ float sA[C_CH][R_RK];          // reparametrized A (6 KB)
    __shared__ float sB[C_CH];                // reparametrized beta
    __shared__ v2 sT[CSLICES][R_RK][64];      // partial T, v2 per lane (32 KB)

    const int tid = threadIdx.x;

    // Reparametrize params into LDS (tiny)
    for (int i = tid; i < C_CH * R_RK; i += NTHR) {
        float a = fmaxf(A[i], BOUND_A_F);
        sA[i >> 3][i & 7] = a * a - PEDESTAL_F;
    }
    for (int i = tid; i < C_CH; i += NTHR) {
        float b = fmaxf(beta[i], BOUND_BETA_F);
        sB[i] = b * b - PEDESTAL_F;
    }
    __syncthreads();

    const int blk  = blockIdx.x;
    const int n    = blk / BLOCKS_PER_IMG;
    const int p0   = (blk % BLOCKS_PER_IMG) * PXB;
    const int lane = tid & 63;
    const int cs   = tid >> 6;          // channel slice 0..7 (uniform per wave)
    const int c0   = cs * CPT;

    const float* xn = x   + (size_t)n * (C_CH * HW) + p0 + (size_t)c0 * HW + 2 * lane;
    float*       on = out + (size_t)n * (C_CH * HW) + p0 + (size_t)c0 * HW + 2 * lane;

    // ---- load 24 channels x 2 px into registers ----
    v2 xr[CPT];
#pragma unroll
    for (int i = 0; i < CPT; ++i) {
        xr[i] = *reinterpret_cast<const v2*>(xn + (size_t)i * HW);
    }

    // ---- accumulate partial T ----
    v2 T[R_RK];
#pragma unroll
    for (int r = 0; r < R_RK; ++r) T[r] = (v2)0.f;

#pragma unroll
    for (int i = 0; i < CPT; ++i) {
        v2 s = xr[i] * xr[i];
#pragma unroll
        for (int r = 0; r < R_RK; ++r) {
            T[r] += s * sA[c0 + i][r];     // uniform LDS addr -> broadcast; fma
        }
    }

    // ---- cross-slice reduce: write partials, fold 8->4, sum 4 ----
#pragma unroll
    for (int r = 0; r < R_RK; ++r) {
        sT[cs][r][lane] = T[r];            // b64 write, lanes consecutive: free
    }
    __syncthreads();

    if (cs < 4) {
#pragma unroll
        for (int r = 0; r < R_RK; ++r) {
            T[r] += sT[cs + 4][r][lane];
            sT[cs][r][lane] = T[r];
        }
    }
    __syncthreads();

    // final Tf reuses T registers
#pragma unroll
    for (int r = 0; r < R_RK; ++r) {
        v2 a01 = sT[0][r][lane] + sT[1][r][lane];
        v2 a23 = sT[2][r][lane] + sT[3][r][lane];
        T[r] = a01 + a23;
    }

    // ---- epilogue: denom + rsqrt + store, all from registers ----
#pragma unroll
    for (int i = 0; i < CPT; ++i) {
        int c = c0 + i;
        v2 d;
        d.x = sB[c];
        d.y = d.x;
#pragma unroll
        for (int r = 0; r < R_RK; ++r) {
            d += sA[c][r] * T[r];
        }
        v2 o;
        o.x = xr[i].x * __builtin_amdgcn_rsqf(d.x);
        o.y = xr[i].y * __builtin_amdgcn_rsqf(d.y);
        __builtin_nontemporal_store(o, reinterpret_cast<v2*>(on + (size_t)i * HW));
    }
}

extern "C" void kernel_launch(void* const* d_in, const int* in_sizes, int n_in,
                              void* d_out, int out_size, void* d_ws, size_t ws_size,
                              hipStream_t stream) {
    const float* x    = (const float*)d_in[0];
    const float* beta = (const float*)d_in[1];
    const float* A    = (const float*)d_in[2];
    float* out = (float*)d_out;

    dim3 grid(N_IMG * BLOCKS_PER_IMG);   // 4096 blocks
    dim3 block(NTHR);                    // 512
    hipLaunchKernelGGL(lrgdn_kernel, grid, block, 0, stream, x, beta, A, out);
}